// Round 1
// baseline (77.798 us; speedup 1.0000x reference)
//
#include <hip/hip_runtime.h>
#include <stdint.h>

// ---------------------------------------------------------------------------
// out[b,t,a,:] = (state_in[b,t,a,:] @ readin[session[b]]) @ project
// Factored: W_b = readin[session[b]] @ project  (192x256), out_b = X_b @ W_b.
// k1 builds W_t[b][o][i] (bf16, K-major for k2's B operand) in d_ws.
// k2 is a batched 128x128-tile bf16-MFMA GEMM, memory-bound target ~40us.
// ---------------------------------------------------------------------------

typedef short    bf16x8 __attribute__((ext_vector_type(8)));
typedef float    f32x4  __attribute__((ext_vector_type(4)));
typedef uint32_t u32x4  __attribute__((ext_vector_type(4)));

#define NB    128   // batch
#define MPB   1024  // rows per batch = T*A
#define INF   192   // K of main GEMM
#define RDIM  64
#define OUTF  256

// round-to-nearest-even f32 -> bf16 bits
__device__ __forceinline__ uint16_t f2bf(float f) {
    union { float f; uint32_t u; } v; v.f = f;
    return (uint16_t)((v.u + 0x7fffu + ((v.u >> 16) & 1u)) >> 16);
}
__device__ __forceinline__ uint32_t pack2(float a, float b) {
    return (uint32_t)f2bf(a) | ((uint32_t)f2bf(b) << 16);
}

// global -> LDS direct copy, 16B per lane. LDS dest must be wave-uniform base.
__device__ __forceinline__ void gl_lds16(const void* g, void* l) {
    auto gp = (const __attribute__((address_space(1))) uint32_t*)(uintptr_t)g;
    auto lp = (__attribute__((address_space(3))) uint32_t*)(uintptr_t)l;
    __builtin_amdgcn_global_load_lds(gp, lp, 16, 0, 0);
}

// ---------------------------------------------------------------------------
// k1: W_t[b][o][i] = sum_h project[h][o] * readin[session[b]][i][h]
// grid 256 = (b:128) x (o-half:2); block 256 thr (4 waves, 2x2 wave grid)
// MFMA D[o][i]: A[o][h] = P^T (transposed into LDS), B[h][i] -> col-major
// B^T[i][h] = readin rows (naturally contiguous).
// ---------------------------------------------------------------------------
__global__ __launch_bounds__(256) void k1_build_w(
    const float* __restrict__ readin,    // [512][192][64]
    const float* __restrict__ project,   // [64][256]
    const int*   __restrict__ session,   // [128]
    uint16_t*    __restrict__ Wt)        // [128][256][192] bf16 bits
{
    __shared__ uint16_t Rl[INF * 64];   // [i][h] bf16, XOR-swizzled, 24KB
    __shared__ uint16_t Pl[128 * 64];   // [o][h] bf16, XOR-swizzled, 16KB

    const int b  = blockIdx.x >> 1;
    const int oh = blockIdx.x & 1;
    const int t  = threadIdx.x;
    const float* Rg = readin + (size_t)session[b] * (INF * RDIM);

    // ---- stage R (192x64 f32 -> bf16 LDS), 16 f32 per thread per chunk ----
#pragma unroll
    for (int c = 0; c < 3; ++c) {
        int idx = c * 4096 + t * 16;       // linear into [192][64]
        int row = idx >> 6;
        int kg0 = (idx & 63) >> 3;         // 16B-slot index (8 bf16 per slot)
        f32x4 v0 = *(const f32x4*)(Rg + idx);
        f32x4 v1 = *(const f32x4*)(Rg + idx + 4);
        f32x4 v2 = *(const f32x4*)(Rg + idx + 8);
        f32x4 v3 = *(const f32x4*)(Rg + idx + 12);
        u32x4 d0, d1;
        d0[0] = pack2(v0[0], v0[1]); d0[1] = pack2(v0[2], v0[3]);
        d0[2] = pack2(v1[0], v1[1]); d0[3] = pack2(v1[2], v1[3]);
        d1[0] = pack2(v2[0], v2[1]); d1[1] = pack2(v2[2], v2[3]);
        d1[2] = pack2(v3[0], v3[1]); d1[3] = pack2(v3[2], v3[3]);
        *(u32x4*)&Rl[row * 64 + (((kg0    ) ^ (row & 7)) << 3)] = d0;
        *(u32x4*)&Rl[row * 64 + (((kg0 + 1) ^ (row & 7)) << 3)] = d1;
    }

    // ---- stage P transposed: Pl[o][h] = project[h][oh*128+o] ----
    {
        int h  = t >> 2;
        int og = (t & 3) * 32;
        const float* Pg = project + (size_t)h * OUTF + oh * 128 + og;
#pragma unroll
        for (int q = 0; q < 8; ++q) {
            f32x4 v = *(const f32x4*)(Pg + q * 4);
#pragma unroll
            for (int e = 0; e < 4; ++e) {
                int o = og + q * 4 + e;
                Pl[o * 64 + (((h >> 3) ^ (o & 7)) << 3) + (h & 7)] = f2bf(v[e]);
            }
        }
    }
    __syncthreads();

    // ---- MFMA: wave tile 64(o) x 96(i), K=64 (2 sub-steps) ----
    const int l  = t & 63, w = t >> 6;
    const int wm = w >> 1, wn = w & 1;
    const int lr = l & 15, lk = l >> 4;

    f32x4 acc[4][6];
#pragma unroll
    for (int m = 0; m < 4; ++m)
#pragma unroll
        for (int n = 0; n < 6; ++n) acc[m][n] = f32x4{0.f, 0.f, 0.f, 0.f};

#pragma unroll
    for (int kk = 0; kk < 2; ++kk) {
        int kg = kk * 4 + lk;
        bf16x8 a[4], bb[6];
#pragma unroll
        for (int m = 0; m < 4; ++m) {
            int row = wm * 64 + m * 16 + lr;
            a[m] = *(const bf16x8*)&Pl[row * 64 + ((kg ^ (row & 7)) << 3)];
        }
#pragma unroll
        for (int n = 0; n < 6; ++n) {
            int col = wn * 96 + n * 16 + lr;
            bb[n] = *(const bf16x8*)&Rl[col * 64 + ((kg ^ (col & 7)) << 3)];
        }
#pragma unroll
        for (int m = 0; m < 4; ++m)
#pragma unroll
            for (int n = 0; n < 6; ++n)
                acc[m][n] = __builtin_amdgcn_mfma_f32_16x16x32_bf16(
                    a[m], bb[n], acc[m][n], 0, 0, 0);
    }

    // ---- store W_t bf16: D row=o=(lane>>4)*4+j, col=i=lane&15 ----
    uint16_t* Wb = Wt + ((size_t)b * OUTF + oh * 128) * INF;
#pragma unroll
    for (int m = 0; m < 4; ++m) {
        int o = wm * 64 + m * 16 + lk * 4;
#pragma unroll
        for (int n = 0; n < 6; ++n) {
            int i = wn * 96 + n * 16 + lr;
#pragma unroll
            for (int j = 0; j < 4; ++j)
                Wb[(size_t)(o + j) * INF + i] = f2bf(acc[m][n][j]);
        }
    }
}

// ---------------------------------------------------------------------------
// k2: out[b] (1024x256) = X[b] (1024x192, f32) @ W_t[b] (bf16)
// grid 2048 = b*16 + mt*2 + nt; block 256 thr (2x2 waves), tile 128x128,
// BK=64 (3 steps), double-buffered LDS. A reg-staged f32->bf16 (swizzled
// ds_write_b128); B global_load_lds w=16 with pre-swizzled global source.
// ---------------------------------------------------------------------------
__global__ __launch_bounds__(256) void k2_gemm(
    const float*    __restrict__ X,    // [128][1024][192]
    const uint16_t* __restrict__ Wt,   // [128][256][192] bf16
    float*          __restrict__ Y)    // [128][1024][256]
{
    __shared__ uint16_t As[2][128 * 64];  // [m][k] swizzled, 16KB each
    __shared__ uint16_t Bs[2][128 * 64];  // [n][k] swizzled, 16KB each

    const int bid = blockIdx.x;
    const int b  = bid >> 4;
    const int mt = (bid >> 1) & 7;
    const int nt = bid & 1;
    const int t  = threadIdx.x, l = t & 63, w = t >> 6;

    const float*    Xb = X  + ((size_t)b * MPB  + mt * 128) * INF;
    const uint16_t* Wb = Wt + ((size_t)b * OUTF + nt * 128) * INF;
    float*          Yb = Y  + ((size_t)b * MPB  + mt * 128) * OUTF + nt * 128;

    const int arow = t >> 1, ahalf = t & 1;

    auto stageB = [&](int ks, int buf) {
        // 16 chunks of 1KB; wave w issues chunks w*4 .. w*4+3 (uniform dest)
#pragma unroll
        for (int j = 0; j < 4; ++j) {
            int c  = w * 4 + j;
            int n  = c * 8 + (l >> 3);
            int kg = (l & 7) ^ (l >> 3);   // inverse-swizzled source slot
            gl_lds16(Wb + (size_t)n * INF + ks * 64 + kg * 8,
                     &Bs[buf][c * 512]);
        }
    };
    auto stageA = [&](int ks, int buf) {
        const float* src = Xb + (size_t)arow * INF + ks * 64 + ahalf * 32;
        f32x4 v[8];
#pragma unroll
        for (int q = 0; q < 8; ++q) v[q] = *(const f32x4*)(src + q * 4);
#pragma unroll
        for (int s = 0; s < 4; ++s) {
            u32x4 d;
            d[0] = pack2(v[2*s  ][0], v[2*s  ][1]);
            d[1] = pack2(v[2*s  ][2], v[2*s  ][3]);
            d[2] = pack2(v[2*s+1][0], v[2*s+1][1]);
            d[3] = pack2(v[2*s+1][2], v[2*s+1][3]);
            int kg = ahalf * 4 + s;
            *(u32x4*)&As[buf][arow * 64 + ((kg ^ (arow & 7)) << 3)] = d;
        }
    };

    stageB(0, 0);
    stageA(0, 0);
    __syncthreads();

    const int wm = w >> 1, wn = w & 1;
    const int lr = l & 15, lk = l >> 4;

    f32x4 acc[4][4];
#pragma unroll
    for (int m = 0; m < 4; ++m)
#pragma unroll
        for (int n = 0; n < 4; ++n) acc[m][n] = f32x4{0.f, 0.f, 0.f, 0.f};

    for (int ks = 0; ks < 3; ++ks) {
        int cur = ks & 1;
        if (ks < 2) { stageB(ks + 1, cur ^ 1); stageA(ks + 1, cur ^ 1); }
#pragma unroll
        for (int kk = 0; kk < 2; ++kk) {
            int kg = kk * 4 + lk;
            bf16x8 af[4], bf_[4];
#pragma unroll
            for (int m = 0; m < 4; ++m) {
                int row = wm * 64 + m * 16 + lr;
                af[m] = *(const bf16x8*)&As[cur][row * 64 + ((kg ^ (row & 7)) << 3)];
            }
#pragma unroll
            for (int n = 0; n < 4; ++n) {
                int col = wn * 64 + n * 16 + lr;
                bf_[n] = *(const bf16x8*)&Bs[cur][col * 64 + ((kg ^ (col & 7)) << 3)];
            }
#pragma unroll
            for (int m = 0; m < 4; ++m)
#pragma unroll
                for (int n = 0; n < 4; ++n)
                    acc[m][n] = __builtin_amdgcn_mfma_f32_16x16x32_bf16(
                        af[m], bf_[n], acc[m][n], 0, 0, 0);
        }
        __syncthreads();
    }

    // epilogue: D row=(lane>>4)*4+j, col=lane&15
#pragma unroll
    for (int m = 0; m < 4; ++m) {
        int r0 = wm * 64 + m * 16 + lk * 4;
#pragma unroll
        for (int n = 0; n < 4; ++n) {
            int c0 = wn * 64 + n * 16 + lr;
#pragma unroll
            for (int j = 0; j < 4; ++j)
                Yb[(size_t)(r0 + j) * OUTF + c0] = acc[m][n][j];
        }
    }
}

extern "C" void kernel_launch(void* const* d_in, const int* in_sizes, int n_in,
                              void* d_out, int out_size, void* d_ws, size_t ws_size,
                              hipStream_t stream) {
    (void)in_sizes; (void)n_in; (void)out_size; (void)ws_size;
    const float* state   = (const float*)d_in[0];
    const int*   session = (const int*)  d_in[1];
    const float* readin  = (const float*)d_in[2];
    const float* project = (const float*)d_in[3];
    float*    out = (float*)d_out;
    uint16_t* Wt  = (uint16_t*)d_ws;   // 128*256*192*2 B = 12.6 MB scratch

    hipLaunchKernelGGL(k1_build_w, dim3(256), dim3(256), 0, stream,
                       readin, project, session, Wt);
    hipLaunchKernelGGL(k2_gemm, dim3(2048), dim3(256), 0, stream,
                       state, Wt, out);
}